// Round 5
// baseline (685.663 us; speedup 1.0000x reference)
//
#include <hip/hip_runtime.h>

typedef unsigned short ushort_t;
typedef __attribute__((ext_vector_type(8))) short short8;
typedef __attribute__((ext_vector_type(4))) float f32x4;
typedef __attribute__((ext_vector_type(8))) unsigned short us8;
typedef __attribute__((ext_vector_type(4))) unsigned short us4;

#define SEQ 2048
#define HIDD 2048
#define XLD 3072
#define SCALING 0.08838834764831843f

__device__ __forceinline__ float bf2f(ushort_t u) {
    unsigned int x = ((unsigned int)u) << 16;
    return __builtin_bit_cast(float, x);
}
__device__ __forceinline__ ushort_t f2bf(float f) {
    unsigned int u = __builtin_bit_cast(unsigned int, f);
    u += 0x7fffu + ((u >> 16) & 1u);
    return (ushort_t)(u >> 16);
}

// ---------------- Convert f32 -> bf16 (vectorized) ---------------------------
__global__ __launch_bounds__(256) void cvt_f32_bf16(
    const float* __restrict__ in, ushort_t* __restrict__ out, int n) {
    int i = (blockIdx.x * 256 + threadIdx.x) * 4;
    if (i < n) {
        float4 v = *(const float4*)(in + i);
        us4 o;
        o[0] = f2bf(v.x); o[1] = f2bf(v.y); o[2] = f2bf(v.z); o[3] = f2bf(v.w);
        *(us4*)(out + i) = o;
    }
}

// ------- Transpose + convert: W (K x N) f32 row-major -> Wt (N x K) bf16 -----
__global__ __launch_bounds__(256) void transpose_f32_bf16(
    const float* __restrict__ W, ushort_t* __restrict__ Wt, int K, int N) {
    __shared__ ushort_t t[64 * 80];
    const int tid = threadIdx.x;
    const int k0 = blockIdx.y * 64;
    const int n0 = blockIdx.x * 64;
    {
        const int kl = tid >> 4;          // 0..15
        const int nc = (tid & 15) * 4;    // 0..60
        #pragma unroll
        for (int p = 0; p < 4; ++p) {
            int k = kl + p * 16;
            float4 v = *(const float4*)(W + (size_t)(k0 + k) * N + n0 + nc);
            t[(nc + 0) * 80 + k] = f2bf(v.x);
            t[(nc + 1) * 80 + k] = f2bf(v.y);
            t[(nc + 2) * 80 + k] = f2bf(v.z);
            t[(nc + 3) * 80 + k] = f2bf(v.w);
        }
    }
    __syncthreads();
    {
        const int nl = tid >> 3;          // 0..31
        const int kc = (tid & 7) * 8;     // 0..56
        #pragma unroll
        for (int p = 0; p < 2; ++p) {
            int n = nl + p * 32;
            *(us8*)(Wt + (size_t)(n0 + n) * K + k0 + kc) = *(const us8*)&t[n * 80 + kc];
        }
    }
}

// ---------------- GEMM: C(MxN) = A(MxK) * Bt(NxK)^T, bf16 in, fp32 accum -----
// 128x128 block tile, BK=32, 4 waves each 64x64 via 4x4 of mfma 16x16x32.
// Output: bf16 (Cb) if Cb != null, else f32 (Cf).
__global__ __launch_bounds__(256) void gemm_bt(
    const ushort_t* __restrict__ A, int lda,
    const ushort_t* __restrict__ Bt, int ldb,
    ushort_t* __restrict__ Cb, float* __restrict__ Cf, int ldc, int K) {
    __shared__ ushort_t lA[128 * 40];
    __shared__ ushort_t lB[128 * 40];
    const int tid = threadIdx.x;
    const int wave = tid >> 6, lane = tid & 63;
    const int wm = wave >> 1, wn = wave & 1;
    const int quad = lane >> 4, l16 = lane & 15;
    const int m0 = blockIdx.y * 128, n0 = blockIdx.x * 128;
    const int srow = tid >> 2;        // 0..63
    const int skc = (tid & 3) * 8;    // 0,8,16,24

    f32x4 acc[4][4] = {};

    for (int kk = 0; kk < K; kk += 32) {
        __syncthreads();
        #pragma unroll
        for (int p = 0; p < 2; ++p) {
            int row = p * 64 + srow;
            *(us8*)&lA[row * 40 + skc] =
                *(const us8*)(A + (size_t)(m0 + row) * lda + kk + skc);
            *(us8*)&lB[row * 40 + skc] =
                *(const us8*)(Bt + (size_t)(n0 + row) * ldb + kk + skc);
        }
        __syncthreads();
        short8 af[4], bfr[4];
        #pragma unroll
        for (int mt = 0; mt < 4; ++mt)
            af[mt] = *(const short8*)&lA[(wm * 64 + mt * 16 + l16) * 40 + quad * 8];
        #pragma unroll
        for (int nt = 0; nt < 4; ++nt)
            bfr[nt] = *(const short8*)&lB[(wn * 64 + nt * 16 + l16) * 40 + quad * 8];
        #pragma unroll
        for (int mt = 0; mt < 4; ++mt) {
            #pragma unroll
            for (int nt = 0; nt < 4; ++nt)
                acc[mt][nt] = __builtin_amdgcn_mfma_f32_16x16x32_bf16(
                    af[mt], bfr[nt], acc[mt][nt], 0, 0, 0);
        }
    }

    // epilogue: C/D layout col=lane&15, row=quad*4+reg
    #pragma unroll
    for (int mt = 0; mt < 4; ++mt) {
        #pragma unroll
        for (int nt = 0; nt < 4; ++nt) {
            int gm = m0 + wm * 64 + mt * 16 + quad * 4;
            int gn = n0 + wn * 64 + nt * 16 + l16;
            #pragma unroll
            for (int r = 0; r < 4; ++r) {
                if (Cb) Cb[(size_t)(gm + r) * ldc + gn] = f2bf(acc[mt][nt][r]);
                else    Cf[(size_t)(gm + r) * ldc + gn] = acc[mt][nt][r];
            }
        }
    }
}

// ------------- RoPE in place on Q (16 heads) + K (4 heads) of X (bf16) -------
__global__ __launch_bounds__(256) void rope_kernel(
    ushort_t* __restrict__ X, const float* __restrict__ cosp,
    const float* __restrict__ sinp) {
    int idx = blockIdx.x * 256 + threadIdx.x;   // SEQ*20*64 total
    int d = idx & 63;
    int rem = idx >> 6;
    int hh = rem % 20;
    int s = rem / 20;
    int cb = (hh < 16) ? hh * 128 : 2048 + (hh - 16) * 128;
    ushort_t* row = X + (size_t)s * XLD + cb;
    const float* cr = cosp + (size_t)s * 128;
    const float* sr = sinp + (size_t)s * 128;
    float x1 = bf2f(row[d]), x2 = bf2f(row[d + 64]);
    row[d]      = f2bf(x1 * cr[d]      - x2 * sr[d]);
    row[d + 64] = f2bf(x2 * cr[d + 64] + x1 * sr[d + 64]);
}

// ---------------- Attention: one wave per (head h, query i) ------------------
// allowed cols: sinks {0..min(4,lo)-1} then local [lo, i], lo=max(0,i-32); NJ<=37
// Weights written f32 (output dtype). Am layout = reference's direct reshape:
//   Am[r = h*128 + i/16][c = (i%16)*128 + d]   (bf16 for the Wo MFMA GEMM)
__global__ __launch_bounds__(256) void attn_kernel(
    const ushort_t* __restrict__ X, float* __restrict__ Wts,
    ushort_t* __restrict__ Aout) {
    int g = blockIdx.x * 4 + (threadIdx.x >> 6);
    int lane = threadIdx.x & 63;
    int i = g & (SEQ - 1);
    int h = g >> 11;

    const ushort_t* Q = X + (size_t)i * XLD + h * 128;
    unsigned int qv = *(const unsigned int*)(Q + 2 * lane);
    float q0 = bf2f((ushort_t)(qv & 0xffff));
    float q1 = bf2f((ushort_t)(qv >> 16));

    int lo = i - 32; if (lo < 0) lo = 0;
    int nsink = lo < 4 ? lo : 4;
    int NJ = nsink + (i - lo + 1);

    const ushort_t* Kbase = X + 2048 + (h >> 2) * 128;
    const ushort_t* Vbase = X + 2560 + (h >> 2) * 128;

    float m = -1e30f, mysc = -1e30f;
    int myj = 0;
    for (int jj = 0; jj < NJ; ++jj) {
        int j = (jj < nsink) ? jj : (lo + jj - nsink);
        unsigned int kv = *(const unsigned int*)(Kbase + (size_t)j * XLD + 2 * lane);
        float p = q0 * bf2f((ushort_t)(kv & 0xffff)) + q1 * bf2f((ushort_t)(kv >> 16));
        #pragma unroll
        for (int off = 32; off > 0; off >>= 1) p += __shfl_xor(p, off, 64);
        p *= SCALING;
        if (jj == lane) { mysc = p; myj = j; }
        m = fmaxf(m, p);
    }
    float e = (lane < NJ) ? expf(mysc - m) : 0.f;
    float l = e;
    #pragma unroll
    for (int off = 32; off > 0; off >>= 1) l += __shfl_xor(l, off, 64);
    float w = e / l;
    if (lane < NJ)
        Wts[((size_t)h * SEQ + i) * SEQ + myj] = w;

    float o0 = 0.f, o1 = 0.f;
    for (int jj = 0; jj < NJ; ++jj) {
        int j = (jj < nsink) ? jj : (lo + jj - nsink);
        float pb = __shfl(w, jj, 64);
        unsigned int vv = *(const unsigned int*)(Vbase + (size_t)j * XLD + 2 * lane);
        o0 += pb * bf2f((ushort_t)(vv & 0xffff));
        o1 += pb * bf2f((ushort_t)(vv >> 16));
    }
    int r = h * 128 + (i >> 4);
    int c = (i & 15) * 128 + 2 * lane;
    ushort_t* Ar = Aout + (size_t)r * HIDD + c;
    Ar[0] = f2bf(o0);
    Ar[1] = f2bf(o1);
}

extern "C" void kernel_launch(void* const* d_in, const int* in_sizes, int n_in,
                              void* d_out, int out_size, void* d_ws, size_t ws_size,
                              hipStream_t stream) {
    if (n_in < 7) return;
    const float* hid  = (const float*)d_in[0];   // all inputs f32 per reference
    const float* cosp = (const float*)d_in[1];
    const float* sinp = (const float*)d_in[2];
    const float* Wq   = (const float*)d_in[3];
    const float* Wk   = (const float*)d_in[4];
    const float* Wv   = (const float*)d_in[5];
    const float* Wo   = (const float*)d_in[6];

    float* out = (float*)d_out;                  // attn_output: 2048*2048 (f32)
    float* wts = out + (size_t)SEQ * HIDD;       // attn_weights: 16*2048*2048 (f32)

    // workspace layout (bf16 elems)
    ushort_t* Hb  = (ushort_t*)d_ws;             // 2048*2048 hidden in bf16
    ushort_t* Wqt = Hb  + (size_t)2048 * 2048;   // 2048*2048
    ushort_t* Wkt = Wqt + (size_t)2048 * 2048;   // 512*2048
    ushort_t* Wvt = Wkt + (size_t)512 * 2048;    // 512*2048
    ushort_t* Wot = Wvt + (size_t)512 * 2048;    // 2048*2048
    ushort_t* X   = Wot + (size_t)2048 * 2048;   // 2048*3072 (Q|K|V)
    ushort_t* Am  = X + (size_t)SEQ * XLD;       // 2048*2048 (direct-reshape rows)
    size_t need = ((size_t)(Am - Hb) + (size_t)SEQ * HIDD) * 2;
    if (ws_size < need) return;

    dim3 blk(256);
    // hidden f32 -> bf16
    cvt_f32_bf16<<<(HIDD * SEQ) / (256 * 4), blk, 0, stream>>>(hid, Hb, HIDD * SEQ);

    // transposes (+convert): grid (N/64, K/64)
    transpose_f32_bf16<<<dim3(32, 32), blk, 0, stream>>>(Wq, Wqt, 2048, 2048);
    transpose_f32_bf16<<<dim3(8, 32),  blk, 0, stream>>>(Wk, Wkt, 2048, 512);
    transpose_f32_bf16<<<dim3(8, 32),  blk, 0, stream>>>(Wv, Wvt, 2048, 512);
    transpose_f32_bf16<<<dim3(32, 32), blk, 0, stream>>>(Wo, Wot, 2048, 2048);

    // QKV projections into X (bf16 out)
    gemm_bt<<<dim3(16, 16), blk, 0, stream>>>(Hb, HIDD, Wqt, 2048, X,        nullptr, XLD, 2048);
    gemm_bt<<<dim3(4, 16),  blk, 0, stream>>>(Hb, HIDD, Wkt, 2048, X + 2048, nullptr, XLD, 2048);
    gemm_bt<<<dim3(4, 16),  blk, 0, stream>>>(Hb, HIDD, Wvt, 2048, X + 2560, nullptr, XLD, 2048);

    // RoPE on Q + K heads
    rope_kernel<<<(SEQ * 20 * 64) / 256, blk, 0, stream>>>(X, cosp, sinp);

    // zero dense f32 weights, then scatter the <=37 nonzeros per row
    hipMemsetAsync(wts, 0, (size_t)16 * SEQ * SEQ * 4, stream);
    attn_kernel<<<(SEQ * 16) / 4, blk, 0, stream>>>(X, wts, Am);

    // output projection -> f32 out
    gemm_bt<<<dim3(16, 16), blk, 0, stream>>>(Am, HIDD, Wot, 2048, nullptr, out, HIDD, 2048);
}

// Round 6
// 589.137 us; speedup vs baseline: 1.1638x; 1.1638x over previous
//
#include <hip/hip_runtime.h>

typedef unsigned short ushort_t;
typedef __attribute__((ext_vector_type(8))) short short8;
typedef __attribute__((ext_vector_type(4))) float f32x4;
typedef __attribute__((ext_vector_type(8))) unsigned short us8;
typedef __attribute__((ext_vector_type(4))) unsigned short us4;

#define SEQ 2048
#define HIDD 2048
#define XLD 3072
#define SCALING 0.08838834764831843f

__device__ __forceinline__ float bf2f(ushort_t u) {
    unsigned int x = ((unsigned int)u) << 16;
    return __builtin_bit_cast(float, x);
}
__device__ __forceinline__ ushort_t f2bf(float f) {
    unsigned int u = __builtin_bit_cast(unsigned int, f);
    u += 0x7fffu + ((u >> 16) & 1u);
    return (ushort_t)(u >> 16);
}

// ---------------- Convert f32 -> bf16 (vectorized) ---------------------------
__global__ __launch_bounds__(256) void cvt_f32_bf16(
    const float* __restrict__ in, ushort_t* __restrict__ out, int n) {
    int i = (blockIdx.x * 256 + threadIdx.x) * 4;
    if (i < n) {
        float4 v = *(const float4*)(in + i);
        us4 o;
        o[0] = f2bf(v.x); o[1] = f2bf(v.y); o[2] = f2bf(v.z); o[3] = f2bf(v.w);
        *(us4*)(out + i) = o;
    }
}

// ------- Transpose + convert: W (K x N) f32 row-major -> Wt (N x K) bf16 -----
__global__ __launch_bounds__(256) void transpose_f32_bf16(
    const float* __restrict__ W, ushort_t* __restrict__ Wt, int K, int N) {
    __shared__ ushort_t t[64 * 80];
    const int tid = threadIdx.x;
    const int k0 = blockIdx.y * 64;
    const int n0 = blockIdx.x * 64;
    {
        const int kl = tid >> 4;          // 0..15
        const int nc = (tid & 15) * 4;    // 0..60
        #pragma unroll
        for (int p = 0; p < 4; ++p) {
            int k = kl + p * 16;
            float4 v = *(const float4*)(W + (size_t)(k0 + k) * N + n0 + nc);
            t[(nc + 0) * 80 + k] = f2bf(v.x);
            t[(nc + 1) * 80 + k] = f2bf(v.y);
            t[(nc + 2) * 80 + k] = f2bf(v.z);
            t[(nc + 3) * 80 + k] = f2bf(v.w);
        }
    }
    __syncthreads();
    {
        const int nl = tid >> 3;          // 0..31
        const int kc = (tid & 7) * 8;     // 0..56
        #pragma unroll
        for (int p = 0; p < 2; ++p) {
            int n = nl + p * 32;
            *(us8*)(Wt + (size_t)(n0 + n) * K + k0 + kc) = *(const us8*)&t[n * 80 + kc];
        }
    }
}

// ---------------- GEMM: C(MxN) = A(MxK) * Bt(NxK)^T, bf16 in, fp32 accum -----
// 128x128 tile, BK=32, 4 waves (64x64 each, 4x4 mfma 16x16x32).
// Staging via global_load_lds width=16 (m97 structure), unpadded 128x32 LDS
// tiles with XOR k-block swizzle: lane l stages global col-block
// (l&3)^((l>>2)&3) so fragment ds_read_b128 banks are uniform (8/bank).
// Output: bf16 (Cb) if Cb != null, else f32 (Cf).
__global__ __launch_bounds__(256) void gemm_bt(
    const ushort_t* __restrict__ A, int lda,
    const ushort_t* __restrict__ Bt, int ldb,
    ushort_t* __restrict__ Cb, float* __restrict__ Cf, int ldc, int K) {
    __shared__ ushort_t lA[128 * 32];
    __shared__ ushort_t lB[128 * 32];
    const int tid = threadIdx.x;
    const int wave = tid >> 6, lane = tid & 63;
    const int wm = wave >> 1, wn = wave & 1;
    const int quad = lane >> 4, l16 = lane & 15;
    const int m0 = blockIdx.y * 128, n0 = blockIdx.x * 128;

    const int srow = lane >> 2;                      // 0..15 (row within 16-group)
    const int scol = 8 * ((lane & 3) ^ (srow & 3));  // swizzled 16B col-block

    f32x4 acc[4][4] = {};

    const ushort_t* Ab = A  + (size_t)(m0 + wave * 16 + srow) * lda + scol;
    const ushort_t* Bb = Bt + (size_t)(n0 + wave * 16 + srow) * ldb + scol;
    ushort_t* lAw = lA + (wave * 16) * 32;   // wave-uniform LDS bases
    ushort_t* lBw = lB + (wave * 16) * 32;

    const int rsw = (quad ^ (l16 & 3)) * 8;  // reader swizzle slot offset

    for (int kk = 0; kk < K; kk += 32) {
        __syncthreads();
        #pragma unroll
        for (int c = 0; c < 2; ++c) {
            __builtin_amdgcn_global_load_lds(
                (const __attribute__((address_space(1))) unsigned int*)(const void*)
                    (Ab + (size_t)(c * 64) * lda + kk),
                (__attribute__((address_space(3))) unsigned int*)(void*)
                    (lAw + c * 64 * 32), 16, 0, 0);
            __builtin_amdgcn_global_load_lds(
                (const __attribute__((address_space(1))) unsigned int*)(const void*)
                    (Bb + (size_t)(c * 64) * ldb + kk),
                (__attribute__((address_space(3))) unsigned int*)(void*)
                    (lBw + c * 64 * 32), 16, 0, 0);
        }
        __syncthreads();   // drains vmcnt before any fragment read
        short8 af[4], bfr[4];
        #pragma unroll
        for (int mt = 0; mt < 4; ++mt)
            af[mt] = *(const short8*)&lA[(wm * 64 + mt * 16 + l16) * 32 + rsw];
        #pragma unroll
        for (int nt = 0; nt < 4; ++nt)
            bfr[nt] = *(const short8*)&lB[(wn * 64 + nt * 16 + l16) * 32 + rsw];
        #pragma unroll
        for (int mt = 0; mt < 4; ++mt) {
            #pragma unroll
            for (int nt = 0; nt < 4; ++nt)
                acc[mt][nt] = __builtin_amdgcn_mfma_f32_16x16x32_bf16(
                    af[mt], bfr[nt], acc[mt][nt], 0, 0, 0);
        }
    }

    // epilogue: C/D layout col=lane&15, row=quad*4+reg
    #pragma unroll
    for (int mt = 0; mt < 4; ++mt) {
        #pragma unroll
        for (int nt = 0; nt < 4; ++nt) {
            int gm = m0 + wm * 64 + mt * 16 + quad * 4;
            int gn = n0 + wn * 64 + nt * 16 + l16;
            #pragma unroll
            for (int r = 0; r < 4; ++r) {
                if (Cb) Cb[(size_t)(gm + r) * ldc + gn] = f2bf(acc[mt][nt][r]);
                else    Cf[(size_t)(gm + r) * ldc + gn] = acc[mt][nt][r];
            }
        }
    }
}

// ------------- RoPE in place on Q (16 heads) + K (4 heads) of X (bf16) -------
__global__ __launch_bounds__(256) void rope_kernel(
    ushort_t* __restrict__ X, const float* __restrict__ cosp,
    const float* __restrict__ sinp) {
    int idx = blockIdx.x * 256 + threadIdx.x;   // SEQ*20*64 total
    int d = idx & 63;
    int rem = idx >> 6;
    int hh = rem % 20;
    int s = rem / 20;
    int cb = (hh < 16) ? hh * 128 : 2048 + (hh - 16) * 128;
    ushort_t* row = X + (size_t)s * XLD + cb;
    const float* cr = cosp + (size_t)s * 128;
    const float* sr = sinp + (size_t)s * 128;
    float x1 = bf2f(row[d]), x2 = bf2f(row[d + 64]);
    row[d]      = f2bf(x1 * cr[d]      - x2 * sr[d]);
    row[d + 64] = f2bf(x2 * cr[d + 64] + x1 * sr[d + 64]);
}

// ---------------- Attention: one wave per (head h, query i) ------------------
// allowed cols: sinks {0..min(4,lo)-1} then local [lo, i], lo=max(0,i-32); NJ<=37
// Weights f32; Am layout = reference's direct reshape (no transpose):
//   Am[r = h*128 + i/16][c = (i%16)*128 + d]   (bf16 for the Wo MFMA GEMM)
__global__ __launch_bounds__(256) void attn_kernel(
    const ushort_t* __restrict__ X, float* __restrict__ Wts,
    ushort_t* __restrict__ Aout) {
    int g = blockIdx.x * 4 + (threadIdx.x >> 6);
    int lane = threadIdx.x & 63;
    int i = g & (SEQ - 1);
    int h = g >> 11;

    const ushort_t* Q = X + (size_t)i * XLD + h * 128;
    unsigned int qv = *(const unsigned int*)(Q + 2 * lane);
    float q0 = bf2f((ushort_t)(qv & 0xffff));
    float q1 = bf2f((ushort_t)(qv >> 16));

    int lo = i - 32; if (lo < 0) lo = 0;
    int nsink = lo < 4 ? lo : 4;
    int NJ = nsink + (i - lo + 1);

    const ushort_t* Kbase = X + 2048 + (h >> 2) * 128;
    const ushort_t* Vbase = X + 2560 + (h >> 2) * 128;

    float m = -1e30f, mysc = -1e30f;
    int myj = 0;
    for (int jj = 0; jj < NJ; ++jj) {
        int j = (jj < nsink) ? jj : (lo + jj - nsink);
        unsigned int kv = *(const unsigned int*)(Kbase + (size_t)j * XLD + 2 * lane);
        float p = q0 * bf2f((ushort_t)(kv & 0xffff)) + q1 * bf2f((ushort_t)(kv >> 16));
        #pragma unroll
        for (int off = 32; off > 0; off >>= 1) p += __shfl_xor(p, off, 64);
        p *= SCALING;
        if (jj == lane) { mysc = p; myj = j; }
        m = fmaxf(m, p);
    }
    float e = (lane < NJ) ? expf(mysc - m) : 0.f;
    float l = e;
    #pragma unroll
    for (int off = 32; off > 0; off >>= 1) l += __shfl_xor(l, off, 64);
    float w = e / l;
    if (lane < NJ)
        Wts[((size_t)h * SEQ + i) * SEQ + myj] = w;

    float o0 = 0.f, o1 = 0.f;
    for (int jj = 0; jj < NJ; ++jj) {
        int j = (jj < nsink) ? jj : (lo + jj - nsink);
        float pb = __shfl(w, jj, 64);
        unsigned int vv = *(const unsigned int*)(Vbase + (size_t)j * XLD + 2 * lane);
        o0 += pb * bf2f((ushort_t)(vv & 0xffff));
        o1 += pb * bf2f((ushort_t)(vv >> 16));
    }
    int r = h * 128 + (i >> 4);
    int c = (i & 15) * 128 + 2 * lane;
    ushort_t* Ar = Aout + (size_t)r * HIDD + c;
    Ar[0] = f2bf(o0);
    Ar[1] = f2bf(o1);
}

extern "C" void kernel_launch(void* const* d_in, const int* in_sizes, int n_in,
                              void* d_out, int out_size, void* d_ws, size_t ws_size,
                              hipStream_t stream) {
    if (n_in < 7) return;
    const float* hid  = (const float*)d_in[0];   // all inputs f32 per reference
    const float* cosp = (const float*)d_in[1];
    const float* sinp = (const float*)d_in[2];
    const float* Wq   = (const float*)d_in[3];
    const float* Wk   = (const float*)d_in[4];
    const float* Wv   = (const float*)d_in[5];
    const float* Wo   = (const float*)d_in[6];

    float* out = (float*)d_out;                  // attn_output: 2048*2048 (f32)
    float* wts = out + (size_t)SEQ * HIDD;       // attn_weights: 16*2048*2048 (f32)

    // workspace layout (bf16 elems); Wqt|Wkt|Wvt contiguous = fused 3072x2048 Bt
    ushort_t* Hb  = (ushort_t*)d_ws;             // 2048*2048 hidden in bf16
    ushort_t* Wqt = Hb  + (size_t)2048 * 2048;   // 2048 rows
    ushort_t* Wkt = Wqt + (size_t)2048 * 2048;   // 512 rows
    ushort_t* Wvt = Wkt + (size_t)512 * 2048;    // 512 rows
    ushort_t* Wot = Wvt + (size_t)512 * 2048;    // 2048*2048
    ushort_t* X   = Wot + (size_t)2048 * 2048;   // 2048*3072 (Q|K|V)
    ushort_t* Am  = X + (size_t)SEQ * XLD;       // 2048*2048 (direct-reshape rows)
    size_t need = ((size_t)(Am - Hb) + (size_t)SEQ * HIDD) * 2;
    if (ws_size < need) return;

    dim3 blk(256);
    // hidden f32 -> bf16
    cvt_f32_bf16<<<(HIDD * SEQ) / (256 * 4), blk, 0, stream>>>(hid, Hb, HIDD * SEQ);

    // transposes (+convert): grid (N/64, K/64)
    transpose_f32_bf16<<<dim3(32, 32), blk, 0, stream>>>(Wq, Wqt, 2048, 2048);
    transpose_f32_bf16<<<dim3(8, 32),  blk, 0, stream>>>(Wk, Wkt, 2048, 512);
    transpose_f32_bf16<<<dim3(8, 32),  blk, 0, stream>>>(Wv, Wvt, 2048, 512);
    transpose_f32_bf16<<<dim3(32, 32), blk, 0, stream>>>(Wo, Wot, 2048, 2048);

    // fused QKV projection: Bt = [Wqt;Wkt;Wvt] (3072 x 2048), C -> X (ldc 3072)
    gemm_bt<<<dim3(24, 16), blk, 0, stream>>>(Hb, HIDD, Wqt, 2048, X, nullptr, XLD, 2048);

    // RoPE on Q + K heads
    rope_kernel<<<(SEQ * 20 * 64) / 256, blk, 0, stream>>>(X, cosp, sinp);

    // zero dense f32 weights, then scatter the <=37 nonzeros per row
    hipMemsetAsync(wts, 0, (size_t)16 * SEQ * SEQ * 4, stream);
    attn_kernel<<<(SEQ * 16) / 4, blk, 0, stream>>>(X, wts, Am);

    // output projection -> f32 out
    gemm_bt<<<dim3(16, 16), blk, 0, stream>>>(Am, HIDD, Wot, 2048, nullptr, out, HIDD, 2048);
}

// Round 7
// 547.279 us; speedup vs baseline: 1.2529x; 1.0765x over previous
//
#include <hip/hip_runtime.h>

typedef unsigned short ushort_t;
typedef __attribute__((ext_vector_type(8))) short short8;
typedef __attribute__((ext_vector_type(4))) float f32x4;
typedef __attribute__((ext_vector_type(8))) unsigned short us8;
typedef __attribute__((ext_vector_type(4))) unsigned short us4;

#define SEQ 2048
#define HIDD 2048
#define XLD 3072
#define SCALING 0.08838834764831843f
#define KSPLIT 1024

__device__ __forceinline__ float bf2f(ushort_t u) {
    unsigned int x = ((unsigned int)u) << 16;
    return __builtin_bit_cast(float, x);
}
__device__ __forceinline__ ushort_t f2bf(float f) {
    unsigned int u = __builtin_bit_cast(unsigned int, f);
    u += 0x7fffu + ((u >> 16) & 1u);
    return (ushort_t)(u >> 16);
}

// ---------------- Convert f32 -> bf16 (vectorized) ---------------------------
__global__ __launch_bounds__(256) void cvt_f32_bf16(
    const float* __restrict__ in, ushort_t* __restrict__ out, int n) {
    int i = (blockIdx.x * 256 + threadIdx.x) * 4;
    if (i < n) {
        float4 v = *(const float4*)(in + i);
        us4 o;
        o[0] = f2bf(v.x); o[1] = f2bf(v.y); o[2] = f2bf(v.z); o[3] = f2bf(v.w);
        *(us4*)(out + i) = o;
    }
}

// ------- Transpose + convert: W (K x N) f32 row-major -> Wt rows, bf16 -------
// Fused over Wq|Wk|Wv into one contiguous (3072 x 2048) Bt when called with
// the 48-wide grid; Wo uses its own launch. Branches are block-uniform.
__device__ __forceinline__ void transpose_tile(
    const float* __restrict__ W, ushort_t* __restrict__ Wt,
    int N, int n0, int k0, int dstRow0) {
    __shared__ ushort_t t[64 * 80];
    const int tid = threadIdx.x;
    {
        const int kl = tid >> 4;          // 0..15
        const int nc = (tid & 15) * 4;    // 0..60
        #pragma unroll
        for (int p = 0; p < 4; ++p) {
            int k = kl + p * 16;
            float4 v = *(const float4*)(W + (size_t)(k0 + k) * N + n0 + nc);
            t[(nc + 0) * 80 + k] = f2bf(v.x);
            t[(nc + 1) * 80 + k] = f2bf(v.y);
            t[(nc + 2) * 80 + k] = f2bf(v.z);
            t[(nc + 3) * 80 + k] = f2bf(v.w);
        }
    }
    __syncthreads();
    {
        const int nl = tid >> 3;          // 0..31
        const int kc = (tid & 7) * 8;     // 0..56
        #pragma unroll
        for (int p = 0; p < 2; ++p) {
            int n = nl + p * 32;
            *(us8*)(Wt + (size_t)(dstRow0 + n) * HIDD + k0 + kc) =
                *(const us8*)&t[n * 80 + kc];
        }
    }
}

__global__ __launch_bounds__(256) void transpose_qkv(
    const float* __restrict__ Wq, const float* __restrict__ Wk,
    const float* __restrict__ Wv, ushort_t* __restrict__ Wt) {
    int bx = blockIdx.x, k0 = blockIdx.y * 64;
    if (bx < 32)       transpose_tile(Wq, Wt, 2048, bx * 64,        k0, bx * 64);
    else if (bx < 40)  transpose_tile(Wk, Wt, 512,  (bx - 32) * 64, k0, 2048 + (bx - 32) * 64);
    else               transpose_tile(Wv, Wt, 512,  (bx - 40) * 64, k0, 2560 + (bx - 40) * 64);
}

__global__ __launch_bounds__(256) void transpose_wo(
    const float* __restrict__ Wo, ushort_t* __restrict__ Wt) {
    transpose_tile(Wo, Wt, 2048, blockIdx.x * 64, blockIdx.y * 64, blockIdx.x * 64);
}

// -------- GEMM split-K: P[z] (MxN f32) = A(:, zK..) * Bt(:, zK..)^T ----------
// 128x128 tile, BK=32, 4 waves, global_load_lds width=16, XOR k-block swizzle.
__global__ __launch_bounds__(256) void gemm_splitk(
    const ushort_t* __restrict__ A, int lda,
    const ushort_t* __restrict__ Bt, int ldb,
    float* __restrict__ P, int ldc) {
    __shared__ ushort_t lA[128 * 32];
    __shared__ ushort_t lB[128 * 32];
    const int tid = threadIdx.x;
    const int wave = tid >> 6, lane = tid & 63;
    const int wm = wave >> 1, wn = wave & 1;
    const int quad = lane >> 4, l16 = lane & 15;
    const int m0 = blockIdx.y * 128, n0 = blockIdx.x * 128;
    const int z = blockIdx.z;

    A  += (size_t)z * KSPLIT;
    Bt += (size_t)z * KSPLIT;
    P  += (size_t)z * ((size_t)gridDim.y * 128) * ldc;

    const int srow = lane >> 2;                      // 0..15
    const int scol = 8 * ((lane & 3) ^ (srow & 3));  // swizzled 16B col-block

    f32x4 acc[4][4] = {};

    const ushort_t* Ab = A  + (size_t)(m0 + wave * 16 + srow) * lda + scol;
    const ushort_t* Bb = Bt + (size_t)(n0 + wave * 16 + srow) * ldb + scol;
    ushort_t* lAw = lA + (wave * 16) * 32;
    ushort_t* lBw = lB + (wave * 16) * 32;

    const int rsw = (quad ^ (l16 & 3)) * 8;

    for (int kk = 0; kk < KSPLIT; kk += 32) {
        __syncthreads();
        #pragma unroll
        for (int c = 0; c < 2; ++c) {
            __builtin_amdgcn_global_load_lds(
                (const __attribute__((address_space(1))) unsigned int*)(const void*)
                    (Ab + (size_t)(c * 64) * lda + kk),
                (__attribute__((address_space(3))) unsigned int*)(void*)
                    (lAw + c * 64 * 32), 16, 0, 0);
            __builtin_amdgcn_global_load_lds(
                (const __attribute__((address_space(1))) unsigned int*)(const void*)
                    (Bb + (size_t)(c * 64) * ldb + kk),
                (__attribute__((address_space(3))) unsigned int*)(void*)
                    (lBw + c * 64 * 32), 16, 0, 0);
        }
        __syncthreads();
        short8 af[4], bfr[4];
        #pragma unroll
        for (int mt = 0; mt < 4; ++mt)
            af[mt] = *(const short8*)&lA[(wm * 64 + mt * 16 + l16) * 32 + rsw];
        #pragma unroll
        for (int nt = 0; nt < 4; ++nt)
            bfr[nt] = *(const short8*)&lB[(wn * 64 + nt * 16 + l16) * 32 + rsw];
        #pragma unroll
        for (int mt = 0; mt < 4; ++mt) {
            #pragma unroll
            for (int nt = 0; nt < 4; ++nt)
                acc[mt][nt] = __builtin_amdgcn_mfma_f32_16x16x32_bf16(
                    af[mt], bfr[nt], acc[mt][nt], 0, 0, 0);
        }
    }

    #pragma unroll
    for (int mt = 0; mt < 4; ++mt) {
        #pragma unroll
        for (int nt = 0; nt < 4; ++nt) {
            int gm = m0 + wm * 64 + mt * 16 + quad * 4;
            int gn = n0 + wn * 64 + nt * 16 + l16;
            #pragma unroll
            for (int r = 0; r < 4; ++r)
                P[(size_t)(gm + r) * ldc + gn] = acc[mt][nt][r];
        }
    }
}

// ---- Split-K reduce + RoPE (f32) + cvt for Q/K head columns of X ------------
__global__ __launch_bounds__(256) void reduce_rope_qk(
    const float* __restrict__ P, ushort_t* __restrict__ X,
    const float* __restrict__ cosp, const float* __restrict__ sinp) {
    const size_t ZS = (size_t)SEQ * XLD;
    int idx = blockIdx.x * 256 + threadIdx.x;   // SEQ*20*64
    int d = idx & 63;
    int rem = idx >> 6;
    int hh = rem % 20;
    int s = rem / 20;
    int cb = (hh < 16) ? hh * 128 : 2048 + (hh - 16) * 128;
    size_t base = (size_t)s * XLD + cb;
    float x1 = P[base + d] + P[ZS + base + d];
    float x2 = P[base + d + 64] + P[ZS + base + d + 64];
    const float* cr = cosp + (size_t)s * 128;
    const float* sr = sinp + (size_t)s * 128;
    X[base + d]      = f2bf(x1 * cr[d]      - x2 * sr[d]);
    X[base + d + 64] = f2bf(x2 * cr[d + 64] + x1 * sr[d + 64]);
}

// ---- Split-K reduce + cvt for V columns of X --------------------------------
__global__ __launch_bounds__(256) void reduce_v(
    const float* __restrict__ P, ushort_t* __restrict__ X) {
    const size_t ZS = (size_t)SEQ * XLD;
    int idx = (blockIdx.x * 256 + threadIdx.x) * 4;  // over SEQ*512
    int c = idx & 511;
    int s = idx >> 9;
    size_t base = (size_t)s * XLD + 2560 + c;
    float4 a = *(const float4*)(P + base);
    float4 b = *(const float4*)(P + ZS + base);
    us4 o;
    o[0] = f2bf(a.x + b.x); o[1] = f2bf(a.y + b.y);
    o[2] = f2bf(a.z + b.z); o[3] = f2bf(a.w + b.w);
    *(us4*)(X + base) = o;
}

// ---- Split-K reduce for the final output (f32) ------------------------------
__global__ __launch_bounds__(256) void reduce_out(
    const float* __restrict__ P, float* __restrict__ out) {
    const size_t ZS = (size_t)SEQ * HIDD;
    int idx = (blockIdx.x * 256 + threadIdx.x) * 4;
    float4 a = *(const float4*)(P + idx);
    float4 b = *(const float4*)(P + ZS + idx);
    float4 o; o.x = a.x + b.x; o.y = a.y + b.y; o.z = a.z + b.z; o.w = a.w + b.w;
    *(float4*)(out + idx) = o;
}

// ---------------- Attention: one wave per (head h, query i) ------------------
// allowed cols: sinks {0..min(4,lo)-1} then local [lo,i], lo=max(0,i-32); NJ<=37
// Writes the FULL dense f32 weights row (zeros included -> no memset needed)
// and Am in the reference's direct-reshape layout (bf16 for the Wo GEMM).
__global__ __launch_bounds__(256) void attn_kernel(
    const ushort_t* __restrict__ X, float* __restrict__ Wts,
    ushort_t* __restrict__ Aout) {
    int g = blockIdx.x * 4 + (threadIdx.x >> 6);
    int lane = threadIdx.x & 63;
    int i = g & (SEQ - 1);
    int h = g >> 11;

    const ushort_t* Q = X + (size_t)i * XLD + h * 128;
    unsigned int qv = *(const unsigned int*)(Q + 2 * lane);
    float q0 = bf2f((ushort_t)(qv & 0xffff));
    float q1 = bf2f((ushort_t)(qv >> 16));

    int lo = i - 32; if (lo < 0) lo = 0;
    int nsink = lo < 4 ? lo : 4;
    int NJ = nsink + (i - lo + 1);

    const ushort_t* Kbase = X + 2048 + (h >> 2) * 128;
    const ushort_t* Vbase = X + 2560 + (h >> 2) * 128;

    float m = -1e30f, mysc = -1e30f;
    for (int jj = 0; jj < NJ; ++jj) {
        int j = (jj < nsink) ? jj : (lo + jj - nsink);
        unsigned int kv = *(const unsigned int*)(Kbase + (size_t)j * XLD + 2 * lane);
        float p = q0 * bf2f((ushort_t)(kv & 0xffff)) + q1 * bf2f((ushort_t)(kv >> 16));
        #pragma unroll
        for (int off = 32; off > 0; off >>= 1) p += __shfl_xor(p, off, 64);
        p *= SCALING;
        if (jj == lane) mysc = p;
        m = fmaxf(m, p);
    }
    float e = (lane < NJ) ? expf(mysc - m) : 0.f;
    float l = e;
    #pragma unroll
    for (int off = 32; off > 0; off >>= 1) l += __shfl_xor(l, off, 64);
    float w = e / l;   // lane jj holds weight for slot jj (jj < NJ)

    // dense weights row: 2048 f32 = 8 slots x (64 lanes x float4)
    float* row = Wts + ((size_t)h * SEQ + i) * SEQ;
    #pragma unroll
    for (int s = 0; s < 8; ++s) {
        float4 o;
        #pragma unroll
        for (int t = 0; t < 4; ++t) {
            int c = s * 256 + lane * 4 + t;
            bool in = (c < nsink) || (c >= lo && c <= i);
            int jjc = in ? ((c < nsink) ? c : (nsink + c - lo)) : 0;
            float wv = __shfl(w, jjc, 64);
            o[t] = in ? wv : 0.f;
        }
        *(float4*)(row + s * 256 + lane * 4) = o;
    }

    float o0 = 0.f, o1 = 0.f;
    for (int jj = 0; jj < NJ; ++jj) {
        int j = (jj < nsink) ? jj : (lo + jj - nsink);
        float pb = __shfl(w, jj, 64);
        unsigned int vv = *(const unsigned int*)(Vbase + (size_t)j * XLD + 2 * lane);
        o0 += pb * bf2f((ushort_t)(vv & 0xffff));
        o1 += pb * bf2f((ushort_t)(vv >> 16));
    }
    int r = h * 128 + (i >> 4);
    int c = (i & 15) * 128 + 2 * lane;
    ushort_t* Ar = Aout + (size_t)r * HIDD + c;
    Ar[0] = f2bf(o0);
    Ar[1] = f2bf(o1);
}

extern "C" void kernel_launch(void* const* d_in, const int* in_sizes, int n_in,
                              void* d_out, int out_size, void* d_ws, size_t ws_size,
                              hipStream_t stream) {
    if (n_in < 7) return;
    const float* hid  = (const float*)d_in[0];
    const float* cosp = (const float*)d_in[1];
    const float* sinp = (const float*)d_in[2];
    const float* Wq   = (const float*)d_in[3];
    const float* Wk   = (const float*)d_in[4];
    const float* Wv   = (const float*)d_in[5];
    const float* Wo   = (const float*)d_in[6];

    float* out = (float*)d_out;                  // attn_output (f32)
    float* wts = out + (size_t)SEQ * HIDD;       // attn_weights (f32)

    // workspace layout
    ushort_t* Hb    = (ushort_t*)d_ws;                    // 2048x2048 bf16
    ushort_t* Wqkvt = Hb    + (size_t)2048 * 2048;        // 3072x2048 bf16
    ushort_t* Wot   = Wqkvt + (size_t)3072 * 2048;        // 2048x2048 bf16
    ushort_t* X     = Wot   + (size_t)2048 * 2048;        // 2048x3072 bf16
    ushort_t* Am    = X     + (size_t)SEQ * XLD;          // 2048x2048 bf16
    float*    Pqkv  = (float*)(Am + (size_t)SEQ * HIDD);  // 2 x 2048x3072 f32
    float*    Pout  = Pqkv + 2 * (size_t)SEQ * XLD;       // 2 x 2048x2048 f32
    size_t need = ((char*)(Pout + 2 * (size_t)SEQ * HIDD)) - (char*)d_ws;
    if (ws_size < need) return;

    dim3 blk(256);
    cvt_f32_bf16<<<(HIDD * SEQ) / (256 * 4), blk, 0, stream>>>(hid, Hb, HIDD * SEQ);
    transpose_qkv<<<dim3(48, 32), blk, 0, stream>>>(Wq, Wk, Wv, Wqkvt);
    transpose_wo<<<dim3(32, 32), blk, 0, stream>>>(Wo, Wot);

    // fused QKV projection, split-K=2 -> f32 partials
    gemm_splitk<<<dim3(24, 16, 2), blk, 0, stream>>>(Hb, HIDD, Wqkvt, 2048, Pqkv, XLD);
    reduce_rope_qk<<<(SEQ * 20 * 64) / 256, blk, 0, stream>>>(Pqkv, X, cosp, sinp);
    reduce_v<<<(SEQ * 512) / (256 * 4), blk, 0, stream>>>(Pqkv, X);

    // attention: dense weights rows (no memset) + Am
    attn_kernel<<<(SEQ * 16) / 4, blk, 0, stream>>>(X, wts, Am);

    // output projection, split-K=2 -> f32 partials -> out
    gemm_splitk<<<dim3(16, 16, 2), blk, 0, stream>>>(Am, HIDD, Wot, 2048, Pout, HIDD);
    reduce_out<<<(SEQ * HIDD) / (256 * 4), blk, 0, stream>>>(Pout, out);
}

// Round 9
// 531.030 us; speedup vs baseline: 1.2912x; 1.0306x over previous
//
#include <hip/hip_runtime.h>

typedef unsigned short ushort_t;
typedef __attribute__((ext_vector_type(8))) short short8;
typedef __attribute__((ext_vector_type(4))) float f32x4;
typedef __attribute__((ext_vector_type(8))) unsigned short us8;
typedef __attribute__((ext_vector_type(4))) unsigned short us4;

#define SEQ 2048
#define HIDD 2048
#define XLD 3072
#define SCALING 0.08838834764831843f

__device__ __forceinline__ float bf2f(ushort_t u) {
    unsigned int x = ((unsigned int)u) << 16;
    return __builtin_bit_cast(float, x);
}
__device__ __forceinline__ ushort_t f2bf(float f) {
    unsigned int u = __builtin_bit_cast(unsigned int, f);
    u += 0x7fffu + ((u >> 16) & 1u);
    return (ushort_t)(u >> 16);
}

// ---------------- Convert f32 -> bf16 (vectorized) ---------------------------
__global__ __launch_bounds__(256) void cvt_f32_bf16(
    const float* __restrict__ in, ushort_t* __restrict__ out, int n) {
    int i = (blockIdx.x * 256 + threadIdx.x) * 4;
    if (i < n) {
        float4 v = *(const float4*)(in + i);
        us4 o;
        o[0] = f2bf(v.x); o[1] = f2bf(v.y); o[2] = f2bf(v.z); o[3] = f2bf(v.w);
        *(us4*)(out + i) = o;
    }
}

// ------- Transpose + convert: W (K x N) f32 row-major -> Wt rows, bf16 -------
__device__ __forceinline__ void transpose_tile(
    const float* __restrict__ W, ushort_t* __restrict__ Wt,
    int N, int n0, int k0, int dstRow0) {
    __shared__ ushort_t t[64 * 80];
    const int tid = threadIdx.x;
    {
        const int kl = tid >> 4;          // 0..15
        const int nc = (tid & 15) * 4;    // 0..60
        #pragma unroll
        for (int p = 0; p < 4; ++p) {
            int k = kl + p * 16;
            float4 v = *(const float4*)(W + (size_t)(k0 + k) * N + n0 + nc);
            t[(nc + 0) * 80 + k] = f2bf(v.x);
            t[(nc + 1) * 80 + k] = f2bf(v.y);
            t[(nc + 2) * 80 + k] = f2bf(v.z);
            t[(nc + 3) * 80 + k] = f2bf(v.w);
        }
    }
    __syncthreads();
    {
        const int nl = tid >> 3;          // 0..31
        const int kc = (tid & 7) * 8;     // 0..56
        #pragma unroll
        for (int p = 0; p < 2; ++p) {
            int n = nl + p * 32;
            *(us8*)(Wt + (size_t)(dstRow0 + n) * HIDD + k0 + kc) =
                *(const us8*)&t[n * 80 + kc];
        }
    }
}

// all four weights in one launch; Wqkvt = [Wq^T;Wk^T;Wv^T] (3072x2048), Wot 2048x2048
__global__ __launch_bounds__(256) void transpose_all(
    const float* __restrict__ Wq, const float* __restrict__ Wk,
    const float* __restrict__ Wv, const float* __restrict__ Wo,
    ushort_t* __restrict__ Wqkvt, ushort_t* __restrict__ Wot) {
    int bx = blockIdx.x, k0 = blockIdx.y * 64;
    if (bx < 32)       transpose_tile(Wq, Wqkvt, 2048, bx * 64,        k0, bx * 64);
    else if (bx < 40)  transpose_tile(Wk, Wqkvt, 512,  (bx - 32) * 64, k0, 2048 + (bx - 32) * 64);
    else if (bx < 48)  transpose_tile(Wv, Wqkvt, 512,  (bx - 40) * 64, k0, 2560 + (bx - 40) * 64);
    else               transpose_tile(Wo, Wot,   2048, (bx - 48) * 64, k0, (bx - 48) * 64);
}

// -------- GEMM split-K: P[z] (MxN f32) = A(:, koff..) * Bt(:, koff..)^T ------
// 128x128 tile, BK=64 (two 128x32 sub-tiles per barrier pair), 4 waves,
// global_load_lds width=16, XOR k-block swizzle. EVERY kext MUST be a
// multiple of 64 (BK) — 672 in r8 double-counted 32 k-cols (absmax 0.30).
__global__ __launch_bounds__(256) void gemm_splitk(
    const ushort_t* __restrict__ A, int lda,
    const ushort_t* __restrict__ Bt, int ldb,
    float* __restrict__ P, int ldc,
    int koff_unit, const int4 kexts) {
    __shared__ ushort_t lA[2 * 128 * 32];
    __shared__ ushort_t lB[2 * 128 * 32];
    const int tid = threadIdx.x;
    const int wave = tid >> 6, lane = tid & 63;
    const int wm = wave >> 1, wn = wave & 1;
    const int quad = lane >> 4, l16 = lane & 15;
    const int m0 = blockIdx.y * 128, n0 = blockIdx.x * 128;
    const int z = blockIdx.z;

    // k-extent per z (supports asymmetric split); koff = prefix sum
    const int ke[4] = {kexts.x, kexts.y, kexts.z, kexts.w};
    int koff = 0;
    for (int zz = 0; zz < 4; ++zz) if (zz < z) koff += ke[zz];
    const int kext = ke[z];
    (void)koff_unit;

    A  += (size_t)koff;
    Bt += (size_t)koff;
    P  += (size_t)z * ((size_t)gridDim.y * 128) * ldc;

    const int srow = lane >> 2;                      // 0..15
    const int scol = 8 * ((lane & 3) ^ (srow & 3));  // swizzled 16B col-block

    f32x4 acc[4][4] = {};

    const ushort_t* Ab = A  + (size_t)(m0 + wave * 16 + srow) * lda + scol;
    const ushort_t* Bb = Bt + (size_t)(n0 + wave * 16 + srow) * ldb + scol;
    ushort_t* lAw = lA + (wave * 16) * 32;
    ushort_t* lBw = lB + (wave * 16) * 32;

    const int rsw = (quad ^ (l16 & 3)) * 8;

    for (int kk = 0; kk < kext; kk += 64) {
        __syncthreads();
        #pragma unroll
        for (int kh = 0; kh < 2; ++kh) {
            #pragma unroll
            for (int c = 0; c < 2; ++c) {
                __builtin_amdgcn_global_load_lds(
                    (const __attribute__((address_space(1))) unsigned int*)(const void*)
                        (Ab + (size_t)(c * 64) * lda + kk + kh * 32),
                    (__attribute__((address_space(3))) unsigned int*)(void*)
                        (lAw + kh * 128 * 32 + c * 64 * 32), 16, 0, 0);
                __builtin_amdgcn_global_load_lds(
                    (const __attribute__((address_space(1))) unsigned int*)(const void*)
                        (Bb + (size_t)(c * 64) * ldb + kk + kh * 32),
                    (__attribute__((address_space(3))) unsigned int*)(void*)
                        (lBw + kh * 128 * 32 + c * 64 * 32), 16, 0, 0);
            }
        }
        __syncthreads();
        #pragma unroll
        for (int kh = 0; kh < 2; ++kh) {
            short8 af[4], bfr[4];
            #pragma unroll
            for (int mt = 0; mt < 4; ++mt)
                af[mt] = *(const short8*)&lA[kh * 128 * 32 + (wm * 64 + mt * 16 + l16) * 32 + rsw];
            #pragma unroll
            for (int nt = 0; nt < 4; ++nt)
                bfr[nt] = *(const short8*)&lB[kh * 128 * 32 + (wn * 64 + nt * 16 + l16) * 32 + rsw];
            #pragma unroll
            for (int mt = 0; mt < 4; ++mt) {
                #pragma unroll
                for (int nt = 0; nt < 4; ++nt)
                    acc[mt][nt] = __builtin_amdgcn_mfma_f32_16x16x32_bf16(
                        af[mt], bfr[nt], acc[mt][nt], 0, 0, 0);
            }
        }
    }

    #pragma unroll
    for (int mt = 0; mt < 4; ++mt) {
        #pragma unroll
        for (int nt = 0; nt < 4; ++nt) {
            int gm = m0 + wm * 64 + mt * 16 + quad * 4;
            int gn = n0 + wn * 64 + nt * 16 + l16;
            #pragma unroll
            for (int r = 0; r < 4; ++r)
                P[(size_t)(gm + r) * ldc + gn] = acc[mt][nt][r];
        }
    }
}

// ---- Fused split-K(2) reduce for X: RoPE path (Q/K cols) + V path -----------
#define ROPE_THREADS (SEQ * 20 * 64)
__global__ __launch_bounds__(256) void reduce_x(
    const float* __restrict__ P, ushort_t* __restrict__ X,
    const float* __restrict__ cosp, const float* __restrict__ sinp) {
    const size_t ZS = (size_t)SEQ * XLD;
    int idx = blockIdx.x * 256 + threadIdx.x;
    if (idx < ROPE_THREADS) {
        int d = idx & 63;
        int rem = idx >> 6;
        int hh = rem % 20;
        int s = rem / 20;
        int cb = (hh < 16) ? hh * 128 : 2048 + (hh - 16) * 128;
        size_t base = (size_t)s * XLD + cb;
        float x1 = P[base + d] + P[ZS + base + d];
        float x2 = P[base + d + 64] + P[ZS + base + d + 64];
        const float* cr = cosp + (size_t)s * 128;
        const float* sr = sinp + (size_t)s * 128;
        X[base + d]      = f2bf(x1 * cr[d]      - x2 * sr[d]);
        X[base + d + 64] = f2bf(x2 * cr[d + 64] + x1 * sr[d + 64]);
    } else {
        int v = (idx - ROPE_THREADS) * 4;   // over SEQ*512
        int c = v & 511;
        int s = v >> 9;
        size_t base = (size_t)s * XLD + 2560 + c;
        float4 a = *(const float4*)(P + base);
        float4 b = *(const float4*)(P + ZS + base);
        us4 o;
        o[0] = f2bf(a.x + b.x); o[1] = f2bf(a.y + b.y);
        o[2] = f2bf(a.z + b.z); o[3] = f2bf(a.w + b.w);
        *(us4*)(X + base) = o;
    }
}

// ---- Split-K(3) reduce for the final output (f32) ---------------------------
__global__ __launch_bounds__(256) void reduce_out3(
    const float* __restrict__ P, float* __restrict__ out) {
    const size_t ZS = (size_t)SEQ * HIDD;
    int idx = (blockIdx.x * 256 + threadIdx.x) * 4;
    float4 a = *(const float4*)(P + idx);
    float4 b = *(const float4*)(P + ZS + idx);
    float4 c = *(const float4*)(P + 2 * ZS + idx);
    float4 o;
    o.x = a.x + b.x + c.x; o.y = a.y + b.y + c.y;
    o.z = a.z + b.z + c.z; o.w = a.w + b.w + c.w;
    *(float4*)(out + idx) = o;
}

// ---------------- Attention: one wave per (head h, query i) ------------------
// allowed cols: sinks {0..min(4,lo)-1} then local [lo,i], lo=max(0,i-32); NJ<=37
// Writes the FULL dense f32 weights row (zeros included -> no memset) and Am in
// the reference's direct-reshape layout: Am[h*128 + i/16][(i%16)*128 + d] (bf16).
__global__ __launch_bounds__(256) void attn_kernel(
    const ushort_t* __restrict__ X, float* __restrict__ Wts,
    ushort_t* __restrict__ Aout) {
    int g = blockIdx.x * 4 + (threadIdx.x >> 6);
    int lane = threadIdx.x & 63;
    int i = g & (SEQ - 1);
    int h = g >> 11;

    const ushort_t* Q = X + (size_t)i * XLD + h * 128;
    unsigned int qv = *(const unsigned int*)(Q + 2 * lane);
    float q0 = bf2f((ushort_t)(qv & 0xffff));
    float q1 = bf2f((ushort_t)(qv >> 16));

    int lo = i - 32; if (lo < 0) lo = 0;
    int nsink = lo < 4 ? lo : 4;
    int NJ = nsink + (i - lo + 1);

    const ushort_t* Kbase = X + 2048 + (h >> 2) * 128;
    const ushort_t* Vbase = X + 2560 + (h >> 2) * 128;

    float m = -1e30f, mysc = -1e30f;
    for (int jj = 0; jj < NJ; ++jj) {
        int j = (jj < nsink) ? jj : (lo + jj - nsink);
        unsigned int kv = *(const unsigned int*)(Kbase + (size_t)j * XLD + 2 * lane);
        float p = q0 * bf2f((ushort_t)(kv & 0xffff)) + q1 * bf2f((ushort_t)(kv >> 16));
        #pragma unroll
        for (int off = 32; off > 0; off >>= 1) p += __shfl_xor(p, off, 64);
        p *= SCALING;
        if (jj == lane) mysc = p;
        m = fmaxf(m, p);
    }
    float e = (lane < NJ) ? expf(mysc - m) : 0.f;
    float l = e;
    #pragma unroll
    for (int off = 32; off > 0; off >>= 1) l += __shfl_xor(l, off, 64);
    float w = e / l;   // lane jj holds weight for slot jj (jj < NJ)

    // dense weights row: 2048 f32 = 8 slots x (64 lanes x float4)
    float* row = Wts + ((size_t)h * SEQ + i) * SEQ;
    #pragma unroll
    for (int s = 0; s < 8; ++s) {
        float4 o;
        #pragma unroll
        for (int t = 0; t < 4; ++t) {
            int c = s * 256 + lane * 4 + t;
            bool in = (c < nsink) || (c >= lo && c <= i);
            int jjc = in ? ((c < nsink) ? c : (nsink + c - lo)) : 0;
            float wv = __shfl(w, jjc, 64);
            o[t] = in ? wv : 0.f;
        }
        *(float4*)(row + s * 256 + lane * 4) = o;
    }

    float o0 = 0.f, o1 = 0.f;
    for (int jj = 0; jj < NJ; ++jj) {
        int j = (jj < nsink) ? jj : (lo + jj - nsink);
        float pb = __shfl(w, jj, 64);
        unsigned int vv = *(const unsigned int*)(Vbase + (size_t)j * XLD + 2 * lane);
        o0 += pb * bf2f((ushort_t)(vv & 0xffff));
        o1 += pb * bf2f((ushort_t)(vv >> 16));
    }
    int r = h * 128 + (i >> 4);
    int c = (i & 15) * 128 + 2 * lane;
    ushort_t* Ar = Aout + (size_t)r * HIDD + c;
    Ar[0] = f2bf(o0);
    Ar[1] = f2bf(o1);
}

extern "C" void kernel_launch(void* const* d_in, const int* in_sizes, int n_in,
                              void* d_out, int out_size, void* d_ws, size_t ws_size,
                              hipStream_t stream) {
    if (n_in < 7) return;
    const float* hid  = (const float*)d_in[0];
    const float* cosp = (const float*)d_in[1];
    const float* sinp = (const float*)d_in[2];
    const float* Wq   = (const float*)d_in[3];
    const float* Wk   = (const float*)d_in[4];
    const float* Wv   = (const float*)d_in[5];
    const float* Wo   = (const float*)d_in[6];

    float* out = (float*)d_out;                  // attn_output (f32)
    float* wts = out + (size_t)SEQ * HIDD;       // attn_weights (f32)

    // workspace layout
    ushort_t* Hb    = (ushort_t*)d_ws;                    // 2048x2048 bf16
    ushort_t* Wqkvt = Hb    + (size_t)2048 * 2048;        // 3072x2048 bf16
    ushort_t* Wot   = Wqkvt + (size_t)3072 * 2048;        // 2048x2048 bf16
    ushort_t* X     = Wot   + (size_t)2048 * 2048;        // 2048x3072 bf16
    ushort_t* Am    = X     + (size_t)SEQ * XLD;          // 2048x2048 bf16
    float*    Pqkv  = (float*)(Am + (size_t)SEQ * HIDD);  // 2 x 2048x3072 f32
    float*    Pout  = Pqkv + 2 * (size_t)SEQ * XLD;       // 3 x 2048x2048 f32
    size_t need = ((char*)(Pout + 3 * (size_t)SEQ * HIDD)) - (char*)d_ws;
    if (ws_size < need) return;

    dim3 blk(256);
    cvt_f32_bf16<<<(HIDD * SEQ) / (256 * 4), blk, 0, stream>>>(hid, Hb, HIDD * SEQ);
    transpose_all<<<dim3(80, 32), blk, 0, stream>>>(Wq, Wk, Wv, Wo, Wqkvt, Wot);

    // fused QKV projection, split-K=2 (1024+1024) -> f32 partials
    gemm_splitk<<<dim3(24, 16, 2), blk, 0, stream>>>(
        Hb, HIDD, Wqkvt, 2048, Pqkv, XLD, 0, make_int4(1024, 1024, 0, 0));
    reduce_x<<<(ROPE_THREADS + SEQ * 512 / 4 + 255) / 256, blk, 0, stream>>>(
        Pqkv, X, cosp, sinp);

    // attention: dense weights rows (no memset) + Am
    attn_kernel<<<(SEQ * 16) / 4, blk, 0, stream>>>(X, wts, Am);

    // output projection, split-K=3 (704+704+640, all x64, full residency)
    gemm_splitk<<<dim3(16, 16, 3), blk, 0, stream>>>(
        Am, HIDD, Wot, 2048, Pout, HIDD, 0, make_int4(704, 704, 640, 0));
    reduce_out3<<<(SEQ * HIDD) / (256 * 4), blk, 0, stream>>>(Pout, out);
}

// Round 10
// 521.671 us; speedup vs baseline: 1.3144x; 1.0179x over previous
//
#include <hip/hip_runtime.h>

typedef unsigned short ushort_t;
typedef __attribute__((ext_vector_type(8))) short short8;
typedef __attribute__((ext_vector_type(4))) float f32x4;
typedef __attribute__((ext_vector_type(8))) unsigned short us8;
typedef __attribute__((ext_vector_type(4))) unsigned short us4;

#define SEQ 2048
#define HIDD 2048
#define XLD 3072
#define SCALING 0.08838834764831843f

__device__ __forceinline__ float bf2f(ushort_t u) {
    unsigned int x = ((unsigned int)u) << 16;
    return __builtin_bit_cast(float, x);
}
__device__ __forceinline__ ushort_t f2bf(float f) {
    unsigned int u = __builtin_bit_cast(unsigned int, f);
    u += 0x7fffu + ((u >> 16) & 1u);
    return (ushort_t)(u >> 16);
}

// ------- Transpose + convert: W (K x N) f32 row-major -> Wt rows, bf16 -------
__device__ __forceinline__ void transpose_tile(
    const float* __restrict__ W, ushort_t* __restrict__ Wt,
    int N, int n0, int k0, int dstRow0) {
    __shared__ ushort_t t[64 * 80];
    const int tid = threadIdx.x;
    {
        const int kl = tid >> 4;          // 0..15
        const int nc = (tid & 15) * 4;    // 0..60
        #pragma unroll
        for (int p = 0; p < 4; ++p) {
            int k = kl + p * 16;
            float4 v = *(const float4*)(W + (size_t)(k0 + k) * N + n0 + nc);
            t[(nc + 0) * 80 + k] = f2bf(v.x);
            t[(nc + 1) * 80 + k] = f2bf(v.y);
            t[(nc + 2) * 80 + k] = f2bf(v.z);
            t[(nc + 3) * 80 + k] = f2bf(v.w);
        }
    }
    __syncthreads();
    {
        const int nl = tid >> 3;          // 0..31
        const int kc = (tid & 7) * 8;     // 0..56
        #pragma unroll
        for (int p = 0; p < 2; ++p) {
            int n = nl + p * 32;
            *(us8*)(Wt + (size_t)(dstRow0 + n) * HIDD + k0 + kc) =
                *(const us8*)&t[n * 80 + kc];
        }
    }
}

// All four weight transposes + the hidden f32->bf16 convert in ONE launch.
// Wqkvt = [Wq^T;Wk^T;Wv^T] (3072x2048), Wot (2048x2048).
// Band bx in [80,112): converts hid (2048x2048 f32) -> Hb bf16 in 4096-elem chunks.
__global__ __launch_bounds__(256) void transpose_all(
    const float* __restrict__ Wq, const float* __restrict__ Wk,
    const float* __restrict__ Wv, const float* __restrict__ Wo,
    const float* __restrict__ hid,
    ushort_t* __restrict__ Wqkvt, ushort_t* __restrict__ Wot,
    ushort_t* __restrict__ Hb) {
    int bx = blockIdx.x, k0 = blockIdx.y * 64;
    if (bx < 32)       transpose_tile(Wq, Wqkvt, 2048, bx * 64,        k0, bx * 64);
    else if (bx < 40)  transpose_tile(Wk, Wqkvt, 512,  (bx - 32) * 64, k0, 2048 + (bx - 32) * 64);
    else if (bx < 48)  transpose_tile(Wv, Wqkvt, 512,  (bx - 40) * 64, k0, 2560 + (bx - 40) * 64);
    else if (bx < 80)  transpose_tile(Wo, Wot,   2048, (bx - 48) * 64, k0, (bx - 48) * 64);
    else {
        int chunk = (bx - 80) * 32 + blockIdx.y;   // 0..1023, 4096 floats each
        size_t base = (size_t)chunk * 4096 + threadIdx.x * 16;
        #pragma unroll
        for (int p = 0; p < 4; ++p) {
            float4 v = *(const float4*)(hid + base + p * 4);
            us4 o;
            o[0] = f2bf(v.x); o[1] = f2bf(v.y); o[2] = f2bf(v.z); o[3] = f2bf(v.w);
            *(us4*)(Hb + base + p * 4) = o;
        }
    }
}

// -------- GEMM split-K: P[z] (MxN bf16) = A(:, koff..) * Bt(:, koff..)^T -----
// 128x128 tile, BK=64 (two 128x32 sub-tiles per barrier pair), 4 waves,
// global_load_lds width=16, XOR k-block swizzle. EVERY kext MUST be a
// multiple of 64 (BK). Partials stored bf16 (summed in f32 by reducers).
__global__ __launch_bounds__(256) void gemm_splitk(
    const ushort_t* __restrict__ A, int lda,
    const ushort_t* __restrict__ Bt, int ldb,
    ushort_t* __restrict__ P, int ldc,
    const int4 kexts) {
    __shared__ ushort_t lA[2 * 128 * 32];
    __shared__ ushort_t lB[2 * 128 * 32];
    const int tid = threadIdx.x;
    const int wave = tid >> 6, lane = tid & 63;
    const int wm = wave >> 1, wn = wave & 1;
    const int quad = lane >> 4, l16 = lane & 15;
    const int m0 = blockIdx.y * 128, n0 = blockIdx.x * 128;
    const int z = blockIdx.z;

    const int ke[4] = {kexts.x, kexts.y, kexts.z, kexts.w};
    int koff = 0;
    for (int zz = 0; zz < 4; ++zz) if (zz < z) koff += ke[zz];
    const int kext = ke[z];

    A  += (size_t)koff;
    Bt += (size_t)koff;
    P  += (size_t)z * ((size_t)gridDim.y * 128) * ldc;

    const int srow = lane >> 2;                      // 0..15
    const int scol = 8 * ((lane & 3) ^ (srow & 3));  // swizzled 16B col-block

    f32x4 acc[4][4] = {};

    const ushort_t* Ab = A  + (size_t)(m0 + wave * 16 + srow) * lda + scol;
    const ushort_t* Bb = Bt + (size_t)(n0 + wave * 16 + srow) * ldb + scol;
    ushort_t* lAw = lA + (wave * 16) * 32;
    ushort_t* lBw = lB + (wave * 16) * 32;

    const int rsw = (quad ^ (l16 & 3)) * 8;

    for (int kk = 0; kk < kext; kk += 64) {
        __syncthreads();
        #pragma unroll
        for (int kh = 0; kh < 2; ++kh) {
            #pragma unroll
            for (int c = 0; c < 2; ++c) {
                __builtin_amdgcn_global_load_lds(
                    (const __attribute__((address_space(1))) unsigned int*)(const void*)
                        (Ab + (size_t)(c * 64) * lda + kk + kh * 32),
                    (__attribute__((address_space(3))) unsigned int*)(void*)
                        (lAw + kh * 128 * 32 + c * 64 * 32), 16, 0, 0);
                __builtin_amdgcn_global_load_lds(
                    (const __attribute__((address_space(1))) unsigned int*)(const void*)
                        (Bb + (size_t)(c * 64) * ldb + kk + kh * 32),
                    (__attribute__((address_space(3))) unsigned int*)(void*)
                        (lBw + kh * 128 * 32 + c * 64 * 32), 16, 0, 0);
            }
        }
        __syncthreads();
        #pragma unroll
        for (int kh = 0; kh < 2; ++kh) {
            short8 af[4], bfr[4];
            #pragma unroll
            for (int mt = 0; mt < 4; ++mt)
                af[mt] = *(const short8*)&lA[kh * 128 * 32 + (wm * 64 + mt * 16 + l16) * 32 + rsw];
            #pragma unroll
            for (int nt = 0; nt < 4; ++nt)
                bfr[nt] = *(const short8*)&lB[kh * 128 * 32 + (wn * 64 + nt * 16 + l16) * 32 + rsw];
            #pragma unroll
            for (int mt = 0; mt < 4; ++mt) {
                #pragma unroll
                for (int nt = 0; nt < 4; ++nt)
                    acc[mt][nt] = __builtin_amdgcn_mfma_f32_16x16x32_bf16(
                        af[mt], bfr[nt], acc[mt][nt], 0, 0, 0);
            }
        }
    }

    #pragma unroll
    for (int mt = 0; mt < 4; ++mt) {
        #pragma unroll
        for (int nt = 0; nt < 4; ++nt) {
            int gm = m0 + wm * 64 + mt * 16 + quad * 4;
            int gn = n0 + wn * 64 + nt * 16 + l16;
            #pragma unroll
            for (int r = 0; r < 4; ++r)
                P[(size_t)(gm + r) * ldc + gn] = f2bf(acc[mt][nt][r]);
        }
    }
}

// ---- Fused split-K(2) reduce for X: RoPE path (Q/K cols) + V path -----------
#define ROPE_THREADS (SEQ * 20 * 64)
__global__ __launch_bounds__(256) void reduce_x(
    const ushort_t* __restrict__ P, ushort_t* __restrict__ X,
    const float* __restrict__ cosp, const float* __restrict__ sinp) {
    const size_t ZS = (size_t)SEQ * XLD;
    int idx = blockIdx.x * 256 + threadIdx.x;
    if (idx < ROPE_THREADS) {
        int d = idx & 63;
        int rem = idx >> 6;
        int hh = rem % 20;
        int s = rem / 20;
        int cb = (hh < 16) ? hh * 128 : 2048 + (hh - 16) * 128;
        size_t base = (size_t)s * XLD + cb;
        float x1 = bf2f(P[base + d])      + bf2f(P[ZS + base + d]);
        float x2 = bf2f(P[base + d + 64]) + bf2f(P[ZS + base + d + 64]);
        const float* cr = cosp + (size_t)s * 128;
        const float* sr = sinp + (size_t)s * 128;
        X[base + d]      = f2bf(x1 * cr[d]      - x2 * sr[d]);
        X[base + d + 64] = f2bf(x2 * cr[d + 64] + x1 * sr[d + 64]);
    } else {
        int v = (idx - ROPE_THREADS) * 4;   // over SEQ*512
        int c = v & 511;
        int s = v >> 9;
        size_t base = (size_t)s * XLD + 2560 + c;
        us4 a = *(const us4*)(P + base);
        us4 b = *(const us4*)(P + ZS + base);
        us4 o;
        #pragma unroll
        for (int t = 0; t < 4; ++t) o[t] = f2bf(bf2f(a[t]) + bf2f(b[t]));
        *(us4*)(X + base) = o;
    }
}

// ---- Split-K(3) reduce for the final output (bf16 partials -> f32 out) ------
__global__ __launch_bounds__(256) void reduce_out3(
    const ushort_t* __restrict__ P, float* __restrict__ out) {
    const size_t ZS = (size_t)SEQ * HIDD;
    size_t idx = ((size_t)blockIdx.x * 256 + threadIdx.x) * 4;
    us4 a = *(const us4*)(P + idx);
    us4 b = *(const us4*)(P + ZS + idx);
    us4 c = *(const us4*)(P + 2 * ZS + idx);
    float4 o;
    o.x = bf2f(a[0]) + bf2f(b[0]) + bf2f(c[0]);
    o.y = bf2f(a[1]) + bf2f(b[1]) + bf2f(c[1]);
    o.z = bf2f(a[2]) + bf2f(b[2]) + bf2f(c[2]);
    o.w = bf2f(a[3]) + bf2f(b[3]) + bf2f(c[3]);
    *(float4*)(out + idx) = o;
}

// ---------------- Attention: one wave per (head h, query i) ------------------
// allowed cols: sinks {0..min(4,lo)-1} then local [lo,i], lo=max(0,i-32); NJ<=37
// Writes the FULL dense f32 weights row (zeros included -> no memset) and Am in
// the reference's direct-reshape layout: Am[h*128 + i/16][(i%16)*128 + d] (bf16).
__global__ __launch_bounds__(256) void attn_kernel(
    const ushort_t* __restrict__ X, float* __restrict__ Wts,
    ushort_t* __restrict__ Aout) {
    int g = blockIdx.x * 4 + (threadIdx.x >> 6);
    int lane = threadIdx.x & 63;
    int i = g & (SEQ - 1);
    int h = g >> 11;

    const ushort_t* Q = X + (size_t)i * XLD + h * 128;
    unsigned int qv = *(const unsigned int*)(Q + 2 * lane);
    float q0 = bf2f((ushort_t)(qv & 0xffff));
    float q1 = bf2f((ushort_t)(qv >> 16));

    int lo = i - 32; if (lo < 0) lo = 0;
    int nsink = lo < 4 ? lo : 4;
    int NJ = nsink + (i - lo + 1);

    const ushort_t* Kbase = X + 2048 + (h >> 2) * 128;
    const ushort_t* Vbase = X + 2560 + (h >> 2) * 128;

    float m = -1e30f, mysc = -1e30f;
    for (int jj = 0; jj < NJ; ++jj) {
        int j = (jj < nsink) ? jj : (lo + jj - nsink);
        unsigned int kv = *(const unsigned int*)(Kbase + (size_t)j * XLD + 2 * lane);
        float p = q0 * bf2f((ushort_t)(kv & 0xffff)) + q1 * bf2f((ushort_t)(kv >> 16));
        #pragma unroll
        for (int off = 32; off > 0; off >>= 1) p += __shfl_xor(p, off, 64);
        p *= SCALING;
        if (jj == lane) mysc = p;
        m = fmaxf(m, p);
    }
    float e = (lane < NJ) ? expf(mysc - m) : 0.f;
    float l = e;
    #pragma unroll
    for (int off = 32; off > 0; off >>= 1) l += __shfl_xor(l, off, 64);
    float w = e / l;   // lane jj holds weight for slot jj (jj < NJ)

    // dense weights row: 2048 f32 = 8 slots x (64 lanes x float4)
    float* row = Wts + ((size_t)h * SEQ + i) * SEQ;
    #pragma unroll
    for (int s = 0; s < 8; ++s) {
        float4 o;
        #pragma unroll
        for (int t = 0; t < 4; ++t) {
            int c = s * 256 + lane * 4 + t;
            bool in = (c < nsink) || (c >= lo && c <= i);
            int jjc = in ? ((c < nsink) ? c : (nsink + c - lo)) : 0;
            float wv = __shfl(w, jjc, 64);
            o[t] = in ? wv : 0.f;
        }
        *(float4*)(row + s * 256 + lane * 4) = o;
    }

    float o0 = 0.f, o1 = 0.f;
    for (int jj = 0; jj < NJ; ++jj) {
        int j = (jj < nsink) ? jj : (lo + jj - nsink);
        float pb = __shfl(w, jj, 64);
        unsigned int vv = *(const unsigned int*)(Vbase + (size_t)j * XLD + 2 * lane);
        o0 += pb * bf2f((ushort_t)(vv & 0xffff));
        o1 += pb * bf2f((ushort_t)(vv >> 16));
    }
    int r = h * 128 + (i >> 4);
    int c = (i & 15) * 128 + 2 * lane;
    ushort_t* Ar = Aout + (size_t)r * HIDD + c;
    Ar[0] = f2bf(o0);
    Ar[1] = f2bf(o1);
}

extern "C" void kernel_launch(void* const* d_in, const int* in_sizes, int n_in,
                              void* d_out, int out_size, void* d_ws, size_t ws_size,
                              hipStream_t stream) {
    if (n_in < 7) return;
    const float* hid  = (const float*)d_in[0];
    const float* cosp = (const float*)d_in[1];
    const float* sinp = (const float*)d_in[2];
    const float* Wq   = (const float*)d_in[3];
    const float* Wk   = (const float*)d_in[4];
    const float* Wv   = (const float*)d_in[5];
    const float* Wo   = (const float*)d_in[6];

    float* out = (float*)d_out;                  // attn_output (f32)
    float* wts = out + (size_t)SEQ * HIDD;       // attn_weights (f32)

    // workspace layout (all bf16 elems now)
    ushort_t* Hb    = (ushort_t*)d_ws;                    // 2048x2048
    ushort_t* Wqkvt = Hb    + (size_t)2048 * 2048;        // 3072x2048
    ushort_t* Wot   = Wqkvt + (size_t)3072 * 2048;        // 2048x2048
    ushort_t* X     = Wot   + (size_t)2048 * 2048;        // 2048x3072
    ushort_t* Am    = X     + (size_t)SEQ * XLD;          // 2048x2048
    ushort_t* Pqkv  = Am    + (size_t)SEQ * HIDD;         // 2 x 2048x3072
    ushort_t* Pout  = Pqkv  + 2 * (size_t)SEQ * XLD;      // 3 x 2048x2048
    size_t need = ((char*)(Pout + 3 * (size_t)SEQ * HIDD)) - (char*)d_ws;
    if (ws_size < need) return;

    dim3 blk(256);
    // all weight transposes + hidden convert in one launch
    transpose_all<<<dim3(112, 32), blk, 0, stream>>>(
        Wq, Wk, Wv, Wo, hid, Wqkvt, Wot, Hb);

    // fused QKV projection, split-K=2 (1024+1024) -> bf16 partials
    gemm_splitk<<<dim3(24, 16, 2), blk, 0, stream>>>(
        Hb, HIDD, Wqkvt, 2048, Pqkv, XLD, make_int4(1024, 1024, 0, 0));
    reduce_x<<<(ROPE_THREADS + SEQ * 512 / 4) / 256, blk, 0, stream>>>(
        Pqkv, X, cosp, sinp);

    // attention: dense weights rows (no memset) + Am
    attn_kernel<<<(SEQ * 16) / 4, blk, 0, stream>>>(X, wts, Am);

    // output projection, split-K=3 (704+704+640, all x64, full residency)
    gemm_splitk<<<dim3(16, 16, 3), blk, 0, stream>>>(
        Am, HIDD, Wot, 2048, Pout, HIDD, make_int4(704, 704, 640, 0));
    reduce_out3<<<(SEQ * HIDD) / (256 * 4), blk, 0, stream>>>(Pout, out);
}